// Round 13
// baseline (146.675 us; speedup 1.0000x reference)
//
#include <hip/hip_runtime.h>
#include <hip/hip_bf16.h>
#include <stdint.h>

#define B 4
#define N 256
#define D 128
#define H 256
#define MAXE 4096      // edges/batch ~3182 +-54
#define SLOTCAP 256    // triangle slots per row; mean ~60, +13 sigma headroom

typedef __attribute__((ext_vector_type(8))) short bf16x8;
typedef __attribute__((ext_vector_type(4))) float f32x4;

__device__ __forceinline__ ushort f2b(float f) {
  __hip_bfloat16 h = __float2bfloat16(f);
  return *reinterpret_cast<ushort*>(&h);
}
__device__ __forceinline__ float b2f(ushort u) {
  return __uint_as_float(((unsigned)u) << 16);
}

#define SWZ(off, row) ((off) ^ (((row) & 7) << 4))

// ---------------------------------------------------------------- K1: adjacency masks + edges + rowBase + nbr (64-thr blocks);
//     blocks >= B*N convert weights to bf16 transposed.
__global__ __launch_bounds__(64) void k_adj(
    const float* __restrict__ A, const float* __restrict__ W3,
    const float* __restrict__ W4,
    uint64_t* __restrict__ adjMask, unsigned* __restrict__ deg,
    uint8_t* __restrict__ nbr, unsigned* __restrict__ rowBase,
    unsigned* __restrict__ edgeCnt, unsigned* __restrict__ edges,
    ushort* __restrict__ W3T, ushort* __restrict__ W4T) {
  int bid = blockIdx.x, lane = threadIdx.x;
  if (bid >= B * N) {                      // 1024 weight-conversion blocks
    int idx = (bid - B * N) * 64 + lane;   // 65536 total
    if (idx < D * H) {                     // W3T[h][c] = W3[c][h]
      int h = idx >> 7, c = idx & 127;
      W3T[h * D + c] = f2b(W3[c * H + h]);
    } else {                               // W4T[d][h] = W4[h][d]
      int i2 = idx - D * H;
      int d = i2 >> 8, hh = i2 & 255;
      W4T[d * H + hh] = f2b(W4[hh * D + d]);
    }
    return;
  }
  int row = bid;
  int b = row >> 8, j = row & 255;
  const float* Arow = A + (size_t)row * N;
  uint64_t m0 = __ballot(Arow[lane] != 0.0f);
  uint64_t m1 = __ballot(Arow[64 + lane] != 0.0f);
  uint64_t m2 = __ballot(Arow[128 + lane] != 0.0f);
  uint64_t m3 = __ballot(Arow[192 + lane] != 0.0f);
  if (lane == 0) {
    adjMask[row * 4 + 0] = m0; adjMask[row * 4 + 1] = m1;
    adjMask[row * 4 + 2] = m2; adjMask[row * 4 + 3] = m3;
  }
  int c0 = __popcll(m0), c1 = __popcll(m1), c2 = __popcll(m2), c3 = __popcll(m3);
  int total = min(c0 + c1 + c2 + c3, 64);
  if (lane == 0) deg[row] = (unsigned)total;
  uint64_t lt = (1ull << lane) - 1ull;
  uint8_t* nr = nbr + (size_t)row * 64;
  if ((m0 >> lane) & 1) { int s = __popcll(m0 & lt);              if (s < 64) nr[s] = (uint8_t)lane; }
  if ((m1 >> lane) & 1) { int s = c0 + __popcll(m1 & lt);         if (s < 64) nr[s] = (uint8_t)(64+lane); }
  if ((m2 >> lane) & 1) { int s = c0+c1 + __popcll(m2 & lt);      if (s < 64) nr[s] = (uint8_t)(128+lane); }
  if ((m3 >> lane) & 1) { int s = c0+c1+c2 + __popcll(m3 & lt);   if (s < 64) nr[s] = (uint8_t)(192+lane); }
  auto gtm = [&](int c) -> uint64_t {
    int lo = j - c * 64;
    if (lo < 0) return ~0ull;
    if (lo >= 63) return 0ull;
    return ~((2ull << lo) - 1ull);
  };
  uint64_t e0 = m0 & gtm(0), e1 = m1 & gtm(1), e2 = m2 & gtm(2), e3 = m3 & gtm(3);
  int t0c = __popcll(e0), t1c = __popcll(e1), t2c = __popcll(e2);
  int et = t0c + t1c + t2c + __popcll(e3);
  unsigned base = 0;
  if (lane == 0 && et) base = atomicAdd(&edgeCnt[b], (unsigned)et);
  base = (unsigned)__shfl((int)base, 0);
  if (lane == 0) rowBase[row] = base;
  unsigned* eb = edges + (size_t)b * MAXE;
  unsigned tag = ((unsigned)j << 8);
  if ((e0 >> lane) & 1) { unsigned s = base + __popcll(e0 & lt);               if (s < MAXE) eb[s] = tag | (unsigned)lane; }
  if ((e1 >> lane) & 1) { unsigned s = base + t0c + __popcll(e1 & lt);         if (s < MAXE) eb[s] = tag | (unsigned)(64+lane); }
  if ((e2 >> lane) & 1) { unsigned s = base + t0c+t1c + __popcll(e2 & lt);     if (s < MAXE) eb[s] = tag | (unsigned)(128+lane); }
  if ((e3 >> lane) & 1) { unsigned s = base + t0c+t1c+t2c + __popcll(e3 & lt); if (s < MAXE) eb[s] = tag | (unsigned)(192+lane); }
}

// ---------------------------------------------------------------- K2: per-edge MLP2 (MFMA bf16) -> Fp
__global__ __launch_bounds__(256) void k_edge_mlp(
    const float* __restrict__ X, const unsigned* __restrict__ edges,
    const unsigned* __restrict__ edgeCnt,
    const ushort* __restrict__ W3T, const float* __restrict__ b3,
    const ushort* __restrict__ W4T, const float* __restrict__ b4,
    ushort* __restrict__ Fp) {
  __shared__ __align__(16) char smem[12288];
  __shared__ unsigned eLds[16];
  int blk = blockIdx.x;                 // B*256 blocks, 1 tile of 16 edges each
  int b = blk >> 8, tile = blk & 255;
  unsigned cnt = min(edgeCnt[b], (unsigned)MAXE);
  int t0 = tile * 16;
  if ((unsigned)t0 >= cnt) return;      // uniform exit before barriers
  int nE = min(16, (int)(cnt - (unsigned)t0));
  int tid = threadIdx.x;
  int w = tid >> 6, l = tid & 63, r = l & 15, g = l >> 4;
  const float* Xb = X + ((size_t)b * N) * D;

  if (tid < 16) eLds[tid] = (tid < nE) ? edges[(size_t)b * MAXE + t0 + tid] : 0u;
  __syncthreads();
  for (int idx = tid; idx < 16 * 64; idx += 256) {
    int e = idx >> 6, cp = idx & 63;
    unsigned ev = eLds[e];
    int j = (int)((ev >> 8) & 255u), k = (int)(ev & 255u);
    float2 xa = *(const float2*)(Xb + (size_t)j * D + cp * 2);
    float2 xb = *(const float2*)(Xb + (size_t)k * D + cp * 2);
    unsigned pk = (unsigned)f2b(xa.x + xb.x) | ((unsigned)f2b(xa.y + xb.y) << 16);
    *(unsigned*)(smem + e * 256 + SWZ(cp * 4, e)) = pk;
  }
  __syncthreads();
  { // layer 1
    bf16x8 afr[4];
#pragma unroll
    for (int ks = 0; ks < 4; ++ks)
      afr[ks] = *(const bf16x8*)(smem + r * 256 + SWZ(ks * 64 + g * 16, r));
    f32x4 acc[4];
#pragma unroll
    for (int t4 = 0; t4 < 4; ++t4) acc[t4] = (f32x4){0.f, 0.f, 0.f, 0.f};
#pragma unroll
    for (int t4 = 0; t4 < 4; ++t4) {
      int h0 = w * 64 + t4 * 16 + r;
#pragma unroll
      for (int ks = 0; ks < 4; ++ks) {
        bf16x8 bfr = *(const bf16x8*)(W3T + (size_t)h0 * D + ks * 32 + g * 8);
        acc[t4] = __builtin_amdgcn_mfma_f32_16x16x32_bf16(afr[ks], bfr, acc[t4], 0, 0, 0);
      }
    }
#pragma unroll
    for (int t4 = 0; t4 < 4; ++t4) {
      int h0 = w * 64 + t4 * 16 + r;
      float bb = b3[h0];
#pragma unroll
      for (int jj = 0; jj < 4; ++jj) {
        int e = g * 4 + jj;
        float v = fmaxf(acc[t4][jj] + bb, 0.0f);
        *(ushort*)(smem + 4096 + e * 512 + SWZ(h0 * 2, e)) = f2b(v);
      }
    }
  }
  __syncthreads();
  { // layer 2 -> global bf16
    f32x4 acc2[2];
    acc2[0] = (f32x4){0.f, 0.f, 0.f, 0.f};
    acc2[1] = (f32x4){0.f, 0.f, 0.f, 0.f};
#pragma unroll
    for (int ks = 0; ks < 8; ++ks) {
      bf16x8 af = *(const bf16x8*)(smem + 4096 + r * 512 + SWZ(ks * 64 + g * 16, r));
#pragma unroll
      for (int t2 = 0; t2 < 2; ++t2) {
        int d0 = (w * 2 + t2) * 16 + r;
        bf16x8 bfr = *(const bf16x8*)(W4T + (size_t)d0 * H + ks * 32 + g * 8);
        acc2[t2] = __builtin_amdgcn_mfma_f32_16x16x32_bf16(af, bfr, acc2[t2], 0, 0, 0);
      }
    }
#pragma unroll
    for (int t2 = 0; t2 < 2; ++t2) {
      int d0 = (w * 2 + t2) * 16 + r;
      float bb = b4[d0];
#pragma unroll
      for (int jj = 0; jj < 4; ++jj) {
        int e = g * 4 + jj;
        if (e < nE) {
          float v = fmaxf(acc2[t2][jj] + bb, 0.0f);
          Fp[((size_t)b * MAXE + t0 + e) * D + d0] = f2b(v);
        }
      }
    }
  }
}

// ---------------------------------------------------------------- K3: fused tail, 512 threads — one block per node n
// A: waves 0-3 build slot lists + nbr lists. B: X_std + Fp gather (1 row per
// thread-slice). C: W1 GEMV (2 rows/thread). D: in-block BN1. E: W2 GEMV.
// F: in-block BN2 -> out. No atomics, no grid sync.
__global__ __launch_bounds__(512) void k_tail(
    const float* __restrict__ X, const float* __restrict__ eps,
    const ushort* __restrict__ Fp,
    const uint64_t* __restrict__ adjMask, const unsigned* __restrict__ rowBase,
    const unsigned* __restrict__ deg, const uint8_t* __restrict__ nbr,
    const float* __restrict__ W1, const float* __restrict__ b1,
    const float* __restrict__ g1, const float* __restrict__ be1,
    const float* __restrict__ W2, const float* __restrict__ b2,
    const float* __restrict__ g2, const float* __restrict__ be2,
    float* __restrict__ out) {
  __shared__ ushort slotsL[B][SLOTCAP];   // 2 KB
  __shared__ uint8_t nbrL[B][64];         // 256 B
  __shared__ int    listLen[B], degL[B];
  __shared__ float  xr[B][D];             // 2 KB
  __shared__ float  zr[B][H];             // 4 KB
  __shared__ float  redS[8], redQ[8], bcast[2];
  int n = blockIdx.x, tid = threadIdx.x;
  int wv = tid >> 6, lane = tid & 63;

  // ---- Phase A: waves 0-3 build slot list + nbr list for row (b=wv, node n)
  if (wv < B) {
    int row = wv * N + n;
    int dg = (int)deg[row];
    if (lane == 0) degL[wv] = dg;
    uint64_t own0 = adjMask[(size_t)row * 4 + 0];
    uint64_t own1 = adjMask[(size_t)row * 4 + 1];
    uint64_t own2 = adjMask[(size_t)row * 4 + 2];
    uint64_t own3 = adjMask[(size_t)row * 4 + 3];
    uint64_t ej[4] = {0, 0, 0, 0}, cmv[4] = {0, 0, 0, 0};
    unsigned rbj = 0;
    int cnt = 0;
    if (lane < dg) {
      int j = (int)nbr[(size_t)row * 64 + lane];
      nbrL[wv][lane] = (uint8_t)j;
      const uint64_t* mj = adjMask + ((size_t)(wv * N + j)) * 4;
      rbj = rowBase[wv * N + j];
#pragma unroll
      for (int c = 0; c < 4; ++c) {
        int lo = j - c * 64;
        uint64_t gm = (lo < 0) ? ~0ull : (lo >= 63 ? 0ull : ~((2ull << lo) - 1ull));
        ej[c] = mj[c] & gm;
      }
      cmv[0] = ej[0] & own0; cmv[1] = ej[1] & own1;
      cmv[2] = ej[2] & own2; cmv[3] = ej[3] & own3;
      cnt = __popcll(cmv[0]) + __popcll(cmv[1]) + __popcll(cmv[2]) + __popcll(cmv[3]);
    }
    // exclusive scan over 64 lanes
    int off = cnt;
    for (int dd = 1; dd < 64; dd <<= 1) {
      int t = __shfl_up(off, dd);
      if (lane >= dd) off += t;
    }
    int excl = off - cnt;
    int total = __shfl(off, 63);
    if (lane == 63) listLen[wv] = min(total, SLOTCAP);
    if (lane < dg && cnt) {
      int idx = excl, pre = 0;
#pragma unroll
      for (int c = 0; c < 4; ++c) {
        uint64_t e = ej[c], m = cmv[c];
        while (m) {
          int lk = __builtin_ctzll(m);
          m &= m - 1;
          unsigned slot = rbj + (unsigned)(pre + __popcll(e & ((1ull << lk) - 1ull)));
          if (slot < (unsigned)MAXE && idx < SLOTCAP) slotsL[wv][idx++] = (ushort)slot;
        }
        pre += __popcll(e);
      }
    }
  }
  __syncthreads();

  // ---- Phase B: X_std + Fp gather; thread (p, d) owns row p exactly
  {
    int p = tid >> 7, d = tid & 127;
    const float* Xb = X + ((size_t)p * N) * D;
    int dg = degL[p];
    float a0 = (1.0f + eps[0]) * Xb[(size_t)n * D + d];
    float a1 = 0.f, a2 = 0.f, a3 = 0.f;
    int s = 0;
    for (; s + 4 <= dg; s += 4) {
      a0 += Xb[(size_t)nbrL[p][s]     * D + d];
      a1 += Xb[(size_t)nbrL[p][s + 1] * D + d];
      a2 += Xb[(size_t)nbrL[p][s + 2] * D + d];
      a3 += Xb[(size_t)nbrL[p][s + 3] * D + d];
    }
    for (; s < dg; ++s) a0 += Xb[(size_t)nbrL[p][s] * D + d];
    int len = listLen[p];
    const ushort* FpB = Fp + (size_t)p * MAXE * D;
    s = 0;
    for (; s + 4 <= len; s += 4) {
      a0 += b2f(FpB[(size_t)slotsL[p][s]     * D + d]);
      a1 += b2f(FpB[(size_t)slotsL[p][s + 1] * D + d]);
      a2 += b2f(FpB[(size_t)slotsL[p][s + 2] * D + d]);
      a3 += b2f(FpB[(size_t)slotsL[p][s + 3] * D + d]);
    }
    for (; s < len; ++s) a0 += b2f(FpB[(size_t)slotsL[p][s] * D + d]);
    xr[p][d] = (a0 + a1) + (a2 + a3);
  }
  __syncthreads();

  // ---- Phase C: W1 GEMV; thread (half, h) computes rows half*2, half*2+1
  float v0, v1;
  int half = tid >> 8, h = tid & 255;
  int r0 = half * 2, r1 = half * 2 + 1;
  {
    float a0 = b1[h], a1 = a0;
#pragma unroll 4
    for (int c = 0; c < D; c += 4) {
      float w0 = W1[(c + 0) * H + h];
      float w1 = W1[(c + 1) * H + h];
      float w2 = W1[(c + 2) * H + h];
      float w3 = W1[(c + 3) * H + h];
      float4 x0 = *(const float4*)&xr[r0][c];
      float4 x1 = *(const float4*)&xr[r1][c];
      a0 = fmaf(x0.x, w0, fmaf(x0.y, w1, fmaf(x0.z, w2, fmaf(x0.w, w3, a0))));
      a1 = fmaf(x1.x, w0, fmaf(x1.y, w1, fmaf(x1.z, w2, fmaf(x1.w, w3, a1))));
    }
    v0 = fmaxf(a0, 0.f); v1 = fmaxf(a1, 0.f);
  }
  // ---- Phase D: in-block BN1 over 4x256 values (each thread holds 2)
  {
    float s = v0 + v1, q = v0 * v0 + v1 * v1;
    for (int o = 32; o; o >>= 1) { s += __shfl_down(s, o); q += __shfl_down(q, o); }
    if (lane == 0) { redS[wv] = s; redQ[wv] = q; }
    __syncthreads();
    if (tid == 0) {
      float S = 0.f, Q = 0.f;
#pragma unroll
      for (int i = 0; i < 8; ++i) { S += redS[i]; Q += redQ[i]; }
      float mean = S * (1.0f / 1024.0f);
      float var = Q * (1.0f / 1024.0f) - mean * mean;
      float inv = rsqrtf(var + 1e-5f);
      float aa = g1[blockIdx.x] * inv;
      bcast[0] = aa;
      bcast[1] = be1[blockIdx.x] - aa * mean;
    }
    __syncthreads();
    float aa = bcast[0], cc = bcast[1];
    zr[r0][h] = fmaf(aa, v0, cc);
    zr[r1][h] = fmaf(aa, v1, cc);
  }
  __syncthreads();

  // ---- Phase E: W2 GEMV
  {
    float a0 = b2[h], a1 = a0;
#pragma unroll 4
    for (int c = 0; c < H; c += 4) {
      float w0 = W2[(c + 0) * H + h];
      float w1 = W2[(c + 1) * H + h];
      float w2 = W2[(c + 2) * H + h];
      float w3 = W2[(c + 3) * H + h];
      float4 z0 = *(const float4*)&zr[r0][c];
      float4 z1 = *(const float4*)&zr[r1][c];
      a0 = fmaf(z0.x, w0, fmaf(z0.y, w1, fmaf(z0.z, w2, fmaf(z0.w, w3, a0))));
      a1 = fmaf(z1.x, w0, fmaf(z1.y, w1, fmaf(z1.z, w2, fmaf(z1.w, w3, a1))));
    }
    v0 = fmaxf(a0, 0.f); v1 = fmaxf(a1, 0.f);
  }
  // ---- Phase F: in-block BN2 + write out
  {
    float s = v0 + v1, q = v0 * v0 + v1 * v1;
    for (int o = 32; o; o >>= 1) { s += __shfl_down(s, o); q += __shfl_down(q, o); }
    if (lane == 0) { redS[wv] = s; redQ[wv] = q; }
    __syncthreads();
    if (tid == 0) {
      float S = 0.f, Q = 0.f;
#pragma unroll
      for (int i = 0; i < 8; ++i) { S += redS[i]; Q += redQ[i]; }
      float mean = S * (1.0f / 1024.0f);
      float var = Q * (1.0f / 1024.0f) - mean * mean;
      float inv = rsqrtf(var + 1e-5f);
      float aa = g2[blockIdx.x] * inv;
      bcast[0] = aa;
      bcast[1] = be2[blockIdx.x] - aa * mean;
    }
    __syncthreads();
    float aa = bcast[0], cc = bcast[1];
    out[((size_t)(r0 * N + blockIdx.x)) * H + h] = fmaf(aa, v0, cc);
    out[((size_t)(r1 * N + blockIdx.x)) * H + h] = fmaf(aa, v1, cc);
  }
}

// ----------------------------------------------------------------
extern "C" void kernel_launch(void* const* d_in, const int* in_sizes, int n_in,
                              void* d_out, int out_size, void* d_ws, size_t ws_size,
                              hipStream_t stream) {
  const float* A   = (const float*)d_in[0];
  const float* X   = (const float*)d_in[1];
  const float* eps = (const float*)d_in[2];
  const float* W1  = (const float*)d_in[3];
  const float* b1  = (const float*)d_in[4];
  const float* g1  = (const float*)d_in[5];
  const float* be1 = (const float*)d_in[6];
  const float* W2  = (const float*)d_in[7];
  const float* b2  = (const float*)d_in[8];
  const float* g2  = (const float*)d_in[9];
  const float* be2 = (const float*)d_in[10];
  const float* W3  = (const float*)d_in[11];
  const float* b3  = (const float*)d_in[12];
  const float* W4  = (const float*)d_in[13];
  const float* b4  = (const float*)d_in[14];
  float* out = (float*)d_out;

  char* ws = (char*)d_ws;
  auto take = [&](size_t bytes) { char* r = ws; ws += (bytes + 255) & ~(size_t)255; return r; };
  unsigned* edgeCnt = (unsigned*)take(256);
  uint64_t* adjMask = (uint64_t*)take((size_t)B * N * 4 * 8);   // 32 KB
  unsigned* rowBase = (unsigned*)take((size_t)B * N * 4);       // 4 KB
  unsigned* edges   = (unsigned*)take((size_t)B * MAXE * 4);    // 64 KB
  unsigned* deg     = (unsigned*)take((size_t)B * N * 4);       // 4 KB
  uint8_t*  nbr     = (uint8_t*)take((size_t)B * N * 64);       // 64 KB
  ushort*   W3T     = (ushort*)take((size_t)D * H * 2);         // 64 KB
  ushort*   W4T     = (ushort*)take((size_t)D * H * 2);         // 64 KB
  ushort*   Fp      = (ushort*)take((size_t)B * MAXE * D * 2);  // 4 MB

  hipMemsetAsync(edgeCnt, 0, 256, stream);

  k_adj<<<B * N + 1024, 64, 0, stream>>>(
      A, W3, W4, adjMask, deg, nbr, rowBase, edgeCnt, edges, W3T, W4T);
  k_edge_mlp<<<B * 256, 256, 0, stream>>>(
      X, edges, edgeCnt, W3T, b3, W4T, b4, Fp);
  k_tail<<<N, 512, 0, stream>>>(
      X, eps, Fp, adjMask, rowBase, deg, nbr, W1, b1, g1, be1, W2, b2, g2, be2, out);
}

// Round 14
// 135.221 us; speedup vs baseline: 1.0847x; 1.0847x over previous
//
#include <hip/hip_runtime.h>
#include <hip/hip_bf16.h>
#include <stdint.h>

#define B 4
#define N 256
#define D 128
#define H 256
#define MAXE 4096      // edges/batch ~3182 +-54
#define SLOTCAP 256    // triangle slots per row; mean ~60, +13 sigma headroom

typedef __attribute__((ext_vector_type(8))) short bf16x8;
typedef __attribute__((ext_vector_type(4))) float f32x4;

__device__ __forceinline__ ushort f2b(float f) {
  __hip_bfloat16 h = __float2bfloat16(f);
  return *reinterpret_cast<ushort*>(&h);
}
__device__ __forceinline__ float b2f(ushort u) {
  return __uint_as_float(((unsigned)u) << 16);
}

#define SWZ(off, row) ((off) ^ (((row) & 7) << 4))

// ---------------------------------------------------------------- K1: adjacency+edges+rowBase+nbr (wave0) then X_std (all);
//     blocks >= B*N convert weights to bf16 transposed.  [round-12 proven]
__global__ __launch_bounds__(128) void k_adj_xstd(
    const float* __restrict__ A, const float* __restrict__ X,
    const float* __restrict__ eps, const float* __restrict__ W3,
    const float* __restrict__ W4,
    uint64_t* __restrict__ adjMask, unsigned* __restrict__ deg,
    uint8_t* __restrict__ nbr, unsigned* __restrict__ rowBase,
    unsigned* __restrict__ edgeCnt, unsigned* __restrict__ edges,
    ushort* __restrict__ W3T, ushort* __restrict__ W4T,
    float* __restrict__ Xn) {
  int bid = blockIdx.x, tid = threadIdx.x;
  if (bid >= B * N) {                      // 512 weight-conversion blocks
    int idx = (bid - B * N) * 128 + tid;   // 65536 total
    if (idx < D * H) {                     // W3T[h][c] = W3[c][h]
      int h = idx >> 7, c = idx & 127;
      W3T[h * D + c] = f2b(W3[c * H + h]);
    } else {                               // W4T[d][h] = W4[h][d]
      int i2 = idx - D * H;
      int d = i2 >> 8, hh = i2 & 255;
      W4T[d * H + hh] = f2b(W4[hh * D + d]);
    }
    return;
  }
  __shared__ uint8_t nbrL[64];
  __shared__ int degL;
  int row = bid;
  int b = row >> 8, j = row & 255;
  if (tid < 64) {                          // wave 0 builds the row
    int lane = tid;
    const float* Arow = A + (size_t)row * N;
    uint64_t m0 = __ballot(Arow[lane] != 0.0f);
    uint64_t m1 = __ballot(Arow[64 + lane] != 0.0f);
    uint64_t m2 = __ballot(Arow[128 + lane] != 0.0f);
    uint64_t m3 = __ballot(Arow[192 + lane] != 0.0f);
    if (lane == 0) {
      adjMask[row * 4 + 0] = m0; adjMask[row * 4 + 1] = m1;
      adjMask[row * 4 + 2] = m2; adjMask[row * 4 + 3] = m3;
    }
    int c0 = __popcll(m0), c1 = __popcll(m1), c2 = __popcll(m2), c3 = __popcll(m3);
    int total = min(c0 + c1 + c2 + c3, 64);
    if (lane == 0) { deg[row] = (unsigned)total; degL = total; }
    uint64_t lt = (1ull << lane) - 1ull;
    uint8_t* nr = nbr + (size_t)row * 64;
    if ((m0 >> lane) & 1) { int s = __popcll(m0 & lt);              if (s < 64) { nr[s] = (uint8_t)lane;       nbrL[s] = (uint8_t)lane; } }
    if ((m1 >> lane) & 1) { int s = c0 + __popcll(m1 & lt);         if (s < 64) { nr[s] = (uint8_t)(64+lane);  nbrL[s] = (uint8_t)(64+lane); } }
    if ((m2 >> lane) & 1) { int s = c0+c1 + __popcll(m2 & lt);      if (s < 64) { nr[s] = (uint8_t)(128+lane); nbrL[s] = (uint8_t)(128+lane); } }
    if ((m3 >> lane) & 1) { int s = c0+c1+c2 + __popcll(m3 & lt);   if (s < 64) { nr[s] = (uint8_t)(192+lane); nbrL[s] = (uint8_t)(192+lane); } }
    auto gtm = [&](int c) -> uint64_t {
      int lo = j - c * 64;
      if (lo < 0) return ~0ull;
      if (lo >= 63) return 0ull;
      return ~((2ull << lo) - 1ull);
    };
    uint64_t e0 = m0 & gtm(0), e1 = m1 & gtm(1), e2 = m2 & gtm(2), e3 = m3 & gtm(3);
    int t0c = __popcll(e0), t1c = __popcll(e1), t2c = __popcll(e2);
    int et = t0c + t1c + t2c + __popcll(e3);
    unsigned base = 0;
    if (lane == 0 && et) base = atomicAdd(&edgeCnt[b], (unsigned)et);
    base = (unsigned)__shfl((int)base, 0);
    if (lane == 0) rowBase[row] = base;
    unsigned* eb = edges + (size_t)b * MAXE;
    unsigned tag = ((unsigned)j << 8);
    if ((e0 >> lane) & 1) { unsigned s = base + __popcll(e0 & lt);               if (s < MAXE) eb[s] = tag | (unsigned)lane; }
    if ((e1 >> lane) & 1) { unsigned s = base + t0c + __popcll(e1 & lt);         if (s < MAXE) eb[s] = tag | (unsigned)(64+lane); }
    if ((e2 >> lane) & 1) { unsigned s = base + t0c+t1c + __popcll(e2 & lt);     if (s < MAXE) eb[s] = tag | (unsigned)(128+lane); }
    if ((e3 >> lane) & 1) { unsigned s = base + t0c+t1c+t2c + __popcll(e3 & lt); if (s < MAXE) eb[s] = tag | (unsigned)(192+lane); }
  }
  __syncthreads();
  // X_std for this row, d = tid (128 dims), 4-way ILP
  int d = tid;
  int dg = degL;
  const float* Xb = X + ((size_t)b * N) * D;
  float a0 = (1.0f + eps[0]) * Xb[(size_t)j * D + d];
  float a1 = 0.f, a2 = 0.f, a3 = 0.f;
  int s = 0;
  for (; s + 4 <= dg; s += 4) {
    a0 += Xb[(size_t)nbrL[s]     * D + d];
    a1 += Xb[(size_t)nbrL[s + 1] * D + d];
    a2 += Xb[(size_t)nbrL[s + 2] * D + d];
    a3 += Xb[(size_t)nbrL[s + 3] * D + d];
  }
  for (; s < dg; ++s) a0 += Xb[(size_t)nbrL[s] * D + d];
  Xn[(size_t)row * D + d] = (a0 + a1) + (a2 + a3);
}

// ---------------------------------------------------------------- K2: per-edge MLP2 (MFMA bf16) -> Fp  [round-12 proven]
__global__ __launch_bounds__(256) void k_edge_mlp(
    const float* __restrict__ X, const unsigned* __restrict__ edges,
    const unsigned* __restrict__ edgeCnt,
    const ushort* __restrict__ W3T, const float* __restrict__ b3,
    const ushort* __restrict__ W4T, const float* __restrict__ b4,
    ushort* __restrict__ Fp) {
  __shared__ __align__(16) char smem[12288];
  __shared__ unsigned eLds[16];
  int blk = blockIdx.x;                 // B*256 blocks, 1 tile of 16 edges each
  int b = blk >> 8, tile = blk & 255;
  unsigned cnt = min(edgeCnt[b], (unsigned)MAXE);
  int t0 = tile * 16;
  if ((unsigned)t0 >= cnt) return;      // uniform exit before barriers
  int nE = min(16, (int)(cnt - (unsigned)t0));
  int tid = threadIdx.x;
  int w = tid >> 6, l = tid & 63, r = l & 15, g = l >> 4;
  const float* Xb = X + ((size_t)b * N) * D;

  if (tid < 16) eLds[tid] = (tid < nE) ? edges[(size_t)b * MAXE + t0 + tid] : 0u;
  __syncthreads();
  for (int idx = tid; idx < 16 * 64; idx += 256) {
    int e = idx >> 6, cp = idx & 63;
    unsigned ev = eLds[e];
    int j = (int)((ev >> 8) & 255u), k = (int)(ev & 255u);
    float2 xa = *(const float2*)(Xb + (size_t)j * D + cp * 2);
    float2 xb = *(const float2*)(Xb + (size_t)k * D + cp * 2);
    unsigned pk = (unsigned)f2b(xa.x + xb.x) | ((unsigned)f2b(xa.y + xb.y) << 16);
    *(unsigned*)(smem + e * 256 + SWZ(cp * 4, e)) = pk;
  }
  __syncthreads();
  { // layer 1
    bf16x8 afr[4];
#pragma unroll
    for (int ks = 0; ks < 4; ++ks)
      afr[ks] = *(const bf16x8*)(smem + r * 256 + SWZ(ks * 64 + g * 16, r));
    f32x4 acc[4];
#pragma unroll
    for (int t4 = 0; t4 < 4; ++t4) acc[t4] = (f32x4){0.f, 0.f, 0.f, 0.f};
#pragma unroll
    for (int t4 = 0; t4 < 4; ++t4) {
      int h0 = w * 64 + t4 * 16 + r;
#pragma unroll
      for (int ks = 0; ks < 4; ++ks) {
        bf16x8 bfr = *(const bf16x8*)(W3T + (size_t)h0 * D + ks * 32 + g * 8);
        acc[t4] = __builtin_amdgcn_mfma_f32_16x16x32_bf16(afr[ks], bfr, acc[t4], 0, 0, 0);
      }
    }
#pragma unroll
    for (int t4 = 0; t4 < 4; ++t4) {
      int h0 = w * 64 + t4 * 16 + r;
      float bb = b3[h0];
#pragma unroll
      for (int jj = 0; jj < 4; ++jj) {
        int e = g * 4 + jj;
        float v = fmaxf(acc[t4][jj] + bb, 0.0f);
        *(ushort*)(smem + 4096 + e * 512 + SWZ(h0 * 2, e)) = f2b(v);
      }
    }
  }
  __syncthreads();
  { // layer 2 -> global bf16
    f32x4 acc2[2];
    acc2[0] = (f32x4){0.f, 0.f, 0.f, 0.f};
    acc2[1] = (f32x4){0.f, 0.f, 0.f, 0.f};
#pragma unroll
    for (int ks = 0; ks < 8; ++ks) {
      bf16x8 af = *(const bf16x8*)(smem + 4096 + r * 512 + SWZ(ks * 64 + g * 16, r));
#pragma unroll
      for (int t2 = 0; t2 < 2; ++t2) {
        int d0 = (w * 2 + t2) * 16 + r;
        bf16x8 bfr = *(const bf16x8*)(W4T + (size_t)d0 * H + ks * 32 + g * 8);
        acc2[t2] = __builtin_amdgcn_mfma_f32_16x16x32_bf16(af, bfr, acc2[t2], 0, 0, 0);
      }
    }
#pragma unroll
    for (int t2 = 0; t2 < 2; ++t2) {
      int d0 = (w * 2 + t2) * 16 + r;
      float bb = b4[d0];
#pragma unroll
      for (int jj = 0; jj < 4; ++jj) {
        int e = g * 4 + jj;
        if (e < nE) {
          float v = fmaxf(acc2[t2][jj] + bb, 0.0f);
          Fp[((size_t)b * MAXE + t0 + e) * D + d0] = f2b(v);
        }
      }
    }
  }
}

// ---------------------------------------------------------------- K3: fused tail, 512 threads — one block per node n
// A: waves 0-3 build slot lists. B: Fp gather, 1 row per thread-slice
// (chain = len/4 ~ 15 loads; Xn from global). C: W1 GEMV (2 rows/thread).
// D: in-block BN1. E: W2 GEMV. F: in-block BN2 -> out.
__global__ __launch_bounds__(512) void k_tail(
    const float* __restrict__ Xn, const ushort* __restrict__ Fp,
    const uint64_t* __restrict__ adjMask, const unsigned* __restrict__ rowBase,
    const unsigned* __restrict__ deg, const uint8_t* __restrict__ nbr,
    const float* __restrict__ W1, const float* __restrict__ b1,
    const float* __restrict__ g1, const float* __restrict__ be1,
    const float* __restrict__ W2, const float* __restrict__ b2,
    const float* __restrict__ g2, const float* __restrict__ be2,
    float* __restrict__ out) {
  __shared__ ushort slotsL[B][SLOTCAP];   // 2 KB
  __shared__ int    listLen[B];
  __shared__ float  xr[B][D];             // 2 KB
  __shared__ float  zr[B][H];             // 4 KB
  __shared__ float  redS[8], redQ[8], bcast[2];
  int n = blockIdx.x, tid = threadIdx.x;
  int wv = tid >> 6, lane = tid & 63;

  // ---- Phase A: waves 0-3 build slot list for row (b=wv, node n)
  if (wv < B) {
    int row = wv * N + n;
    int dg = (int)deg[row];
    uint64_t own0 = adjMask[(size_t)row * 4 + 0];
    uint64_t own1 = adjMask[(size_t)row * 4 + 1];
    uint64_t own2 = adjMask[(size_t)row * 4 + 2];
    uint64_t own3 = adjMask[(size_t)row * 4 + 3];
    uint64_t ej[4] = {0, 0, 0, 0}, cmv[4] = {0, 0, 0, 0};
    unsigned rbj = 0;
    int cnt = 0;
    if (lane < dg) {
      int j = (int)nbr[(size_t)row * 64 + lane];
      const uint64_t* mj = adjMask + ((size_t)(wv * N + j)) * 4;
      rbj = rowBase[wv * N + j];
#pragma unroll
      for (int c = 0; c < 4; ++c) {
        int lo = j - c * 64;
        uint64_t gm = (lo < 0) ? ~0ull : (lo >= 63 ? 0ull : ~((2ull << lo) - 1ull));
        ej[c] = mj[c] & gm;
      }
      cmv[0] = ej[0] & own0; cmv[1] = ej[1] & own1;
      cmv[2] = ej[2] & own2; cmv[3] = ej[3] & own3;
      cnt = __popcll(cmv[0]) + __popcll(cmv[1]) + __popcll(cmv[2]) + __popcll(cmv[3]);
    }
    // exclusive scan over 64 lanes
    int off = cnt;
    for (int dd = 1; dd < 64; dd <<= 1) {
      int t = __shfl_up(off, dd);
      if (lane >= dd) off += t;
    }
    int excl = off - cnt;
    int total = __shfl(off, 63);
    if (lane == 63) listLen[wv] = min(total, SLOTCAP);
    if (lane < dg && cnt) {
      int idx = excl, pre = 0;
#pragma unroll
      for (int c = 0; c < 4; ++c) {
        uint64_t e = ej[c], m = cmv[c];
        while (m) {
          int lk = __builtin_ctzll(m);
          m &= m - 1;
          unsigned slot = rbj + (unsigned)(pre + __popcll(e & ((1ull << lk) - 1ull)));
          if (slot < (unsigned)MAXE && idx < SLOTCAP) slotsL[wv][idx++] = (ushort)slot;
        }
        pre += __popcll(e);
      }
    }
  }
  __syncthreads();

  // ---- Phase B: Fp gather; thread (p, d) owns row p exactly (4 rows in parallel)
  {
    int p = tid >> 7, d = tid & 127;
    int len = listLen[p];
    const ushort* FpB = Fp + (size_t)p * MAXE * D;
    float a0 = Xn[((size_t)(p * N + n)) * D + d];
    float a1 = 0.f, a2 = 0.f, a3 = 0.f;
    int s = 0;
    for (; s + 4 <= len; s += 4) {
      a0 += b2f(FpB[(size_t)slotsL[p][s]     * D + d]);
      a1 += b2f(FpB[(size_t)slotsL[p][s + 1] * D + d]);
      a2 += b2f(FpB[(size_t)slotsL[p][s + 2] * D + d]);
      a3 += b2f(FpB[(size_t)slotsL[p][s + 3] * D + d]);
    }
    for (; s < len; ++s) a0 += b2f(FpB[(size_t)slotsL[p][s] * D + d]);
    xr[p][d] = (a0 + a1) + (a2 + a3);
  }
  __syncthreads();

  // ---- Phase C: W1 GEMV; thread (half, h) computes rows half*2, half*2+1
  float v0, v1;
  int half = tid >> 8, h = tid & 255;
  int r0 = half * 2, r1 = half * 2 + 1;
  {
    float a0 = b1[h], a1 = a0;
#pragma unroll 4
    for (int c = 0; c < D; c += 4) {
      float w0 = W1[(c + 0) * H + h];
      float w1 = W1[(c + 1) * H + h];
      float w2 = W1[(c + 2) * H + h];
      float w3 = W1[(c + 3) * H + h];
      float4 x0 = *(const float4*)&xr[r0][c];
      float4 x1 = *(const float4*)&xr[r1][c];
      a0 = fmaf(x0.x, w0, fmaf(x0.y, w1, fmaf(x0.z, w2, fmaf(x0.w, w3, a0))));
      a1 = fmaf(x1.x, w0, fmaf(x1.y, w1, fmaf(x1.z, w2, fmaf(x1.w, w3, a1))));
    }
    v0 = fmaxf(a0, 0.f); v1 = fmaxf(a1, 0.f);
  }
  // ---- Phase D: in-block BN1 over 4x256 values (each thread holds 2)
  {
    float s = v0 + v1, q = v0 * v0 + v1 * v1;
    for (int o = 32; o; o >>= 1) { s += __shfl_down(s, o); q += __shfl_down(q, o); }
    if (lane == 0) { redS[wv] = s; redQ[wv] = q; }
    __syncthreads();
    if (tid == 0) {
      float S = 0.f, Q = 0.f;
#pragma unroll
      for (int i = 0; i < 8; ++i) { S += redS[i]; Q += redQ[i]; }
      float mean = S * (1.0f / 1024.0f);
      float var = Q * (1.0f / 1024.0f) - mean * mean;
      float inv = rsqrtf(var + 1e-5f);
      float aa = g1[blockIdx.x] * inv;
      bcast[0] = aa;
      bcast[1] = be1[blockIdx.x] - aa * mean;
    }
    __syncthreads();
    float aa = bcast[0], cc = bcast[1];
    zr[r0][h] = fmaf(aa, v0, cc);
    zr[r1][h] = fmaf(aa, v1, cc);
  }
  __syncthreads();

  // ---- Phase E: W2 GEMV
  {
    float a0 = b2[h], a1 = a0;
#pragma unroll 4
    for (int c = 0; c < H; c += 4) {
      float w0 = W2[(c + 0) * H + h];
      float w1 = W2[(c + 1) * H + h];
      float w2 = W2[(c + 2) * H + h];
      float w3 = W2[(c + 3) * H + h];
      float4 z0 = *(const float4*)&zr[r0][c];
      float4 z1 = *(const float4*)&zr[r1][c];
      a0 = fmaf(z0.x, w0, fmaf(z0.y, w1, fmaf(z0.z, w2, fmaf(z0.w, w3, a0))));
      a1 = fmaf(z1.x, w0, fmaf(z1.y, w1, fmaf(z1.z, w2, fmaf(z1.w, w3, a1))));
    }
    v0 = fmaxf(a0, 0.f); v1 = fmaxf(a1, 0.f);
  }
  // ---- Phase F: in-block BN2 + write out
  {
    float s = v0 + v1, q = v0 * v0 + v1 * v1;
    for (int o = 32; o; o >>= 1) { s += __shfl_down(s, o); q += __shfl_down(q, o); }
    if (lane == 0) { redS[wv] = s; redQ[wv] = q; }
    __syncthreads();
    if (tid == 0) {
      float S = 0.f, Q = 0.f;
#pragma unroll
      for (int i = 0; i < 8; ++i) { S += redS[i]; Q += redQ[i]; }
      float mean = S * (1.0f / 1024.0f);
      float var = Q * (1.0f / 1024.0f) - mean * mean;
      float inv = rsqrtf(var + 1e-5f);
      float aa = g2[blockIdx.x] * inv;
      bcast[0] = aa;
      bcast[1] = be2[blockIdx.x] - aa * mean;
    }
    __syncthreads();
    float aa = bcast[0], cc = bcast[1];
    out[((size_t)(r0 * N + blockIdx.x)) * H + h] = fmaf(aa, v0, cc);
    out[((size_t)(r1 * N + blockIdx.x)) * H + h] = fmaf(aa, v1, cc);
  }
}

// ----------------------------------------------------------------
extern "C" void kernel_launch(void* const* d_in, const int* in_sizes, int n_in,
                              void* d_out, int out_size, void* d_ws, size_t ws_size,
                              hipStream_t stream) {
  const float* A   = (const float*)d_in[0];
  const float* X   = (const float*)d_in[1];
  const float* eps = (const float*)d_in[2];
  const float* W1  = (const float*)d_in[3];
  const float* b1  = (const float*)d_in[4];
  const float* g1  = (const float*)d_in[5];
  const float* be1 = (const float*)d_in[6];
  const float* W2  = (const float*)d_in[7];
  const float* b2  = (const float*)d_in[8];
  const float* g2  = (const float*)d_in[9];
  const float* be2 = (const float*)d_in[10];
  const float* W3  = (const float*)d_in[11];
  const float* b3  = (const float*)d_in[12];
  const float* W4  = (const float*)d_in[13];
  const float* b4  = (const float*)d_in[14];
  float* out = (float*)d_out;

  char* ws = (char*)d_ws;
  auto take = [&](size_t bytes) { char* r = ws; ws += (bytes + 255) & ~(size_t)255; return r; };
  unsigned* edgeCnt = (unsigned*)take(256);
  uint64_t* adjMask = (uint64_t*)take((size_t)B * N * 4 * 8);   // 32 KB
  unsigned* rowBase = (unsigned*)take((size_t)B * N * 4);       // 4 KB
  unsigned* edges   = (unsigned*)take((size_t)B * MAXE * 4);    // 64 KB
  unsigned* deg     = (unsigned*)take((size_t)B * N * 4);       // 4 KB
  uint8_t*  nbr     = (uint8_t*)take((size_t)B * N * 64);       // 64 KB
  ushort*   W3T     = (ushort*)take((size_t)D * H * 2);         // 64 KB
  ushort*   W4T     = (ushort*)take((size_t)D * H * 2);         // 64 KB
  float*    Xn      = (float*)take((size_t)B * N * D * 4);      // 512 KB
  ushort*   Fp      = (ushort*)take((size_t)B * MAXE * D * 2);  // 4 MB

  hipMemsetAsync(edgeCnt, 0, 256, stream);

  k_adj_xstd<<<B * N + 512, 128, 0, stream>>>(
      A, X, eps, W3, W4, adjMask, deg, nbr, rowBase, edgeCnt, edges, W3T, W4T, Xn);
  k_edge_mlp<<<B * 256, 256, 0, stream>>>(
      X, edges, edgeCnt, W3T, b3, W4T, b4, Fp);
  k_tail<<<N, 512, 0, stream>>>(
      Xn, Fp, adjMask, rowBase, deg, nbr, W1, b1, g1, be1, W2, b2, g2, be2, out);
}